// Round 14
// baseline (148.930 us; speedup 1.0000x reference)
//
#include <hip/hip_runtime.h>
#include <hip/hip_bf16.h>
#include <stdint.h>

#define Bb 2
#define Ll 2048
#define Dd 768
#define HID 32
#define BL (Bb*Ll)          // 4096
#define KPAD 32
#define KROWS (KPAD+Ll+16)  // 2096

typedef __hip_bfloat16 bf16;
typedef __attribute__((ext_vector_type(8))) short short8;
typedef __attribute__((ext_vector_type(4))) short short4s;
typedef __attribute__((ext_vector_type(4))) float floatx4;

__device__ __forceinline__ float b2f(short u) {
    union { float f; unsigned i; } x; x.i = ((unsigned)(unsigned short)u) << 16; return x.f;
}
__device__ __forceinline__ bf16 f2b(float x) { return __float2bfloat16(x); }
__device__ __forceinline__ short f2bs(float x) {
    bf16 t = __float2bfloat16(x);
    union { bf16 h; short s; } u; u.h = t; return u.s;
}

typedef __attribute__((address_space(1))) const unsigned int guint;
typedef __attribute__((address_space(3))) unsigned int luint;
__device__ __forceinline__ void gload16(const bf16* g, bf16* l) {
    __builtin_amdgcn_global_load_lds((guint*)g, (luint*)l, 16, 0, 0);
}

// ============ prep (weights->bf16, K/V pads) + gate MLP, fused, independent blocks ============
#define CONV_VB 2304                 // 4*768*768/4 float4 / 256
#define KP_VB   (Bb*48)              // 96
#define VT_VB   ((Bb*Dd*48)/256)     // 288
#define PREP_VB (CONV_VB+KP_VB+VT_VB)   // 2688
#define GATE_VB (BL/8)               // 512
__global__ __launch_bounds__(256) void prep_gate_kernel(
        const float* __restrict__ wq, const float* __restrict__ wk,
        const float* __restrict__ wv, const float* __restrict__ wo,
        const float* __restrict__ bk, const float* __restrict__ bv,
        const float* __restrict__ hidden, const float* __restrict__ sal,
        const float* __restrict__ gw1, const float* __restrict__ gb1,
        const float* __restrict__ gw2, const float* __restrict__ gb2,
        bf16* __restrict__ wout, bf16* __restrict__ kp, bf16* __restrict__ vT,
        bf16* __restrict__ h_b) {
    __shared__ bf16 g2t[32 * 770];      // transposed gw2, row-padded to 770 (bank-clean)
    __shared__ float h1s[8][HID];
    int bx = blockIdx.x, tid = threadIdx.x;
    if (bx < CONV_VB) {
        int idx = bx * 256 + tid;
        const int per = Dd * Dd / 4;
        int w = idx / per, r = idx % per;
        const float* src = (w == 0) ? wq : (w == 1) ? wk : (w == 2) ? wv : wo;
        float4 v = reinterpret_cast<const float4*>(src)[r];
        bf16* o = wout + (size_t)w * Dd * Dd + (size_t)r * 4;
        o[0] = f2b(v.x); o[1] = f2b(v.y); o[2] = f2b(v.z); o[3] = f2b(v.w);
    } else if (bx < CONV_VB + KP_VB) {
        int pb = bx - CONV_VB;
        int b = pb / 48, c = pb % 48;
        int row = (c < 32) ? c : (KPAD + Ll + (c - 32));
        size_t base = ((size_t)b * KROWS + row) * Dd;
        for (int i = tid; i < Dd; i += 256)
            kp[base + i] = (c < 32) ? f2b(bk[i]) : f2b(0.f);
    } else if (bx < PREP_VB) {
        int o = (bx - CONV_VB - KP_VB) * 256 + tid;
        int b = o / (Dd * 48); int rem = o - b * Dd * 48;
        int n = rem / 48, c = rem % 48;
        int col = (c < 32) ? c : (KPAD + Ll + (c - 32));
        vT[((size_t)b * Dd + n) * KROWS + col] = (c < 32) ? f2b(bv[n]) : f2b(0.f);
    } else {
        // ---- gate: 8 rows per block; per-block gw2 transpose into LDS (bf16) ----
        int row0 = (bx - PREP_VB) * 8;
#pragma unroll
        for (int k2 = 0; k2 < 24; ++k2) {              // 768*32 fp32 via float4
            int o4 = tid + k2 * 256;
            float4 v = reinterpret_cast<const float4*>(gw2)[o4];
            int d = o4 >> 3, j = (o4 & 7) * 4;         // flat = d*32 + j
            g2t[(j + 0) * 770 + d] = f2b(v.x);
            g2t[(j + 1) * 770 + d] = f2b(v.y);
            g2t[(j + 2) * 770 + d] = f2b(v.z);
            g2t[(j + 3) * 770 + d] = f2b(v.w);
        }
        {
            int rr = tid >> 5, j = tid & 31;
            float s = sal[row0 + rr];
            float x = s * gw1[j] + gb1[j];
            h1s[rr][j] = x / (1.f + __expf(-x));       // silu
        }
        __syncthreads();
#pragma unroll
        for (int dl = 0; dl < 3; ++dl) {
            int d = tid + dl * 256;
            float base = gb2[d];
            float acc[8];
#pragma unroll
            for (int rr = 0; rr < 8; ++rr) acc[rr] = base;
#pragma unroll
            for (int j = 0; j < HID; ++j) {
                float wj = b2f(*(const short*)&g2t[j * 770 + d]);   // 2-way alias = free
#pragma unroll
                for (int rr = 0; rr < 8; ++rr) acc[rr] += h1s[rr][j] * wj;
            }
#pragma unroll
            for (int rr = 0; rr < 8; ++rr) {
                float g = 1.f / (1.f + __expf(-acc[rr]));
                g = fminf(fmaxf(g, 0.05f), 0.95f);
                size_t off = (size_t)(row0 + rr) * Dd + d;
                h_b[off] = f2b(hidden[off] * g);
            }
        }
    }
}

// ---------------- single-buffer m97-structure GEMM core (max co-residency) ----------------
template<int NF>   // wave n-frags: 4 -> BN=128 (LDS 32KB), 2 -> BN=64 (24KB)
__device__ __forceinline__ void gemm_core(const bf16* __restrict__ Ag, const bf16* __restrict__ Wg,
                                          int m0, int n0, bf16* As, bf16* Bs,
                                          floatx4 (&acc)[4][NF]) {
    const int tid  = threadIdx.x;
    const int wave = tid >> 6, lane = tid & 63;
    const int lrow = lane & 15, koff = (lane >> 4) * 8;
    const int wm = (wave >> 1) * 64, wn = (wave & 1) * (NF * 16);
    const char* Asb = (const char*)As;
    const char* Bsb = (const char*)Bs;

    for (int k0 = 0; k0 < Dd; k0 += 64) {
#pragma unroll
        for (int c = 0; c < 4; ++c) {              // A: 128x64 = 16KB
            int p = tid * 16 + c * 4096;
            int r = p >> 7;
            int o = (p & 127) ^ ((r & 7) << 4);
            gload16(Ag + (size_t)(m0 + r) * Dd + k0 + (o >> 1),
                    As + (wave * 1024 + c * 4096) / 2);
        }
#pragma unroll
        for (int c = 0; c < NF; ++c) {             // B: NF*32 x 64
            int p = tid * 16 + c * 4096;
            int r = p >> 7;
            int o = (p & 127) ^ ((r & 7) << 4);
            gload16(Wg + (size_t)(n0 + r) * Dd + k0 + (o >> 1),
                    Bs + (wave * 1024 + c * 4096) / 2);
        }
        __syncthreads();
#pragma unroll
        for (int kk = 0; kk < 64; kk += 32) {
            short8 a[4], b[NF];
#pragma unroll
            for (int i = 0; i < 4; ++i) {
                int row = wm + i * 16 + lrow;
                int byt = (row << 7) + (((kk + koff) * 2) ^ ((row & 7) << 4));
                a[i] = *reinterpret_cast<const short8*>(Asb + byt);
            }
#pragma unroll
            for (int j = 0; j < NF; ++j) {
                int row = wn + j * 16 + lrow;
                int byt = (row << 7) + (((kk + koff) * 2) ^ ((row & 7) << 4));
                b[j] = *reinterpret_cast<const short8*>(Bsb + byt);
            }
#pragma unroll
            for (int i = 0; i < 4; ++i)
#pragma unroll
                for (int j = 0; j < NF; ++j)
                    acc[i][j] = __builtin_amdgcn_mfma_f32_16x16x32_bf16(a[i], b[j], acc[i][j], 0, 0, 0);
        }
        __syncthreads();
    }
}

// ---------------- fused QKV GEMM (single-buffer, 4 blocks/CU target) ----------------
__global__ __launch_bounds__(256, 4) void gemm_qkv(
        const bf16* __restrict__ A, const bf16* __restrict__ W3,
        const float* __restrict__ bq, const float* __restrict__ bk, const float* __restrict__ bv,
        bf16* __restrict__ qo, bf16* __restrict__ kp, bf16* __restrict__ vT) {
    __shared__ bf16 As[128 * 64];   // 16 KB
    __shared__ bf16 Bs[128 * 64];   // 16 KB
    int bid = blockIdx.x;
    int xcd = bid & 7, idx = bid >> 3;
    int mtile = (xcd >> 1) * 8 + (idx & 7);
    int ntile = (xcd & 1) * 9 + (idx >> 3);
    int tgt = ntile / 6;
    int n0 = (ntile % 6) * 128;
    int m0 = mtile * 128;
    const bf16* W = W3 + (size_t)tgt * Dd * Dd;
    const float* bias = (tgt == 0) ? bq : (tgt == 1) ? bk : bv;

    floatx4 acc[4][4] = {};
    gemm_core<4>(A, W, m0, n0, As, Bs, acc);

    int wave = threadIdx.x >> 6, lane = threadIdx.x & 63;
    int wm = (wave >> 1) * 64, wn = (wave & 1) * 64;
    int crow = (lane >> 4) * 4, ccol = lane & 15;
#pragma unroll
    for (int i = 0; i < 4; ++i)
#pragma unroll
        for (int j = 0; j < 4; ++j) {
            int n = n0 + wn + j * 16 + ccol;
            float bb = bias[n];
            int m = m0 + wm + i * 16 + crow;
            int b_ = m >> 11, l = m & 2047;
            if (tgt == 2) {
                short4s pk;
#pragma unroll
                for (int rr = 0; rr < 4; ++rr) pk[rr] = f2bs(acc[i][j][rr] + bb);
                *reinterpret_cast<short4s*>(vT + ((size_t)b_ * Dd + n) * KROWS + KPAD + l) = pk;
            } else {
#pragma unroll
                for (int rr = 0; rr < 4; ++rr) {
                    size_t orow = (tgt == 0) ? (size_t)(m + rr)
                                             : ((size_t)b_ * KROWS + KPAD + l + rr);
                    bf16* outp = (tgt == 0) ? qo : kp;
                    outp[orow * Dd + n] = f2b(acc[i][j][rr] + bb);
                }
            }
        }
}

// ---------------- output GEMM (single-buffer): out = merged @ wo^T + bo + h ----------------
__global__ __launch_bounds__(256, 4) void gemm_out(
        const bf16* __restrict__ A, const bf16* __restrict__ W,
        const float* __restrict__ bias, const bf16* __restrict__ addend,
        float* __restrict__ out) {
    __shared__ bf16 As[128 * 64];   // 16 KB
    __shared__ bf16 Bs[64 * 64];    // 8 KB
    int bid = blockIdx.x;
    int xcd = bid & 7, idx = bid >> 3;
    int mtile = (xcd >> 1) * 8 + (idx & 7);
    int ntile = (xcd & 1) * 6 + (idx >> 3);
    int n0 = ntile * 64, m0 = mtile * 128;

    floatx4 acc[4][2] = {};
    gemm_core<2>(A, W, m0, n0, As, Bs, acc);

    int wave = threadIdx.x >> 6, lane = threadIdx.x & 63;
    int wm = (wave >> 1) * 64, wn = (wave & 1) * 32;
    int crow = (lane >> 4) * 4, ccol = lane & 15;
#pragma unroll
    for (int i = 0; i < 4; ++i)
#pragma unroll
        for (int j = 0; j < 2; ++j) {
            int n = n0 + wn + j * 16 + ccol;
            float bb = bias[n];
#pragma unroll
            for (int rr = 0; rr < 4; ++rr) {
                int m = m0 + wm + i * 16 + crow + rr;
                size_t o = (size_t)m * Dd + n;
                out[o] = acc[i][j][rr] + bb + b2f(*(const short*)(addend + o));
            }
        }
}

// ---------------- MFMA banded sliding-window attention, 8 waves per group ----------------
#define AW 8
__global__ __launch_bounds__(512) void attn_kernel(
        const bf16* __restrict__ q, const bf16* __restrict__ kp, const bf16* __restrict__ vT,
        bf16* __restrict__ merged) {
    __shared__ float Sp[AW][16][66];       // partial scores; stride 66 -> 2-way banks (free)
    __shared__ bf16 wlds[AW][16 * 64];     // per-wave W~ bounce, XOR-swizzled
    const int tid = threadIdx.x;
    const int wv = tid >> 6, lane = tid & 63;
    const int bid = blockIdx.x;                    // 256
    const int g = (bid & 7) * 32 + (bid >> 3);     // XCD-chunked, bijective
    const int b = g >> 7, L0 = (g & 127) * 16;
    const int lrow = lane & 15, koff = (lane >> 4) * 8;
    const int crow = (lane >> 4) * 4, ccol = lane & 15;
    const float scale = 0.03608439182435161f;      // 1/sqrt(768)

    // ---- QK^T partial: wave wv covers k-dims [wv*96, wv*96+96)
    const bf16* qbase = q  + ((size_t)(b * Ll + L0 + lrow)) * Dd + koff + wv * 96;
    const bf16* kbase = kp + ((size_t)b * KROWS + L0 + lrow) * Dd + koff + wv * 96;
    floatx4 s4[4] = {};
#pragma unroll
    for (int ks = 0; ks < 3; ++ks) {
        short8 a = *reinterpret_cast<const short8*>(qbase + ks * 32);
#pragma unroll
        for (int f = 0; f < 4; ++f) {
            short8 bb = *reinterpret_cast<const short8*>(kbase + (size_t)f * 16 * Dd + ks * 32);
            s4[f] = __builtin_amdgcn_mfma_f32_16x16x32_bf16(a, bb, s4[f], 0, 0, 0);
        }
    }
#pragma unroll
    for (int f = 0; f < 4; ++f)
#pragma unroll
        for (int rr = 0; rr < 4; ++rr)
            Sp[wv][crow + rr][f * 16 + ccol] = s4[f][rr];
    __syncthreads();

    // ---- banded softmax (redundant per wave), rows r = crow+rr; lane col j = f*16+ccol
#pragma unroll
    for (int rr = 0; rr < 4; ++rr) {
        int r = crow + rr;
        float z[4], e[4];
#pragma unroll
        for (int f = 0; f < 4; ++f) {
            int j = f * 16 + ccol;
            float v = 0.f;
#pragma unroll
            for (int w = 0; w < AW; ++w) v += Sp[w][r][j];
            bool valid = (j >= r + 1) && (j <= r + 32);
            z[f] = valid ? v * scale : -3.0e38f;
        }
        float m = fmaxf(fmaxf(z[0], z[1]), fmaxf(z[2], z[3]));
#pragma unroll
        for (int off = 1; off < 16; off <<= 1) m = fmaxf(m, __shfl_xor(m, off));
        float S32 = 0.f, S8 = 0.f;
#pragma unroll
        for (int f = 0; f < 4; ++f) {
            e[f] = __expf(z[f] - m);
            S32 += e[f];
            int j = f * 16 + ccol;
            S8 += ((j >= r + 25) && (j <= r + 32)) ? e[f] : 0.f;
        }
#pragma unroll
        for (int off = 1; off < 16; off <<= 1) {
            S32 += __shfl_xor(S32, off);
            S8  += __shfl_xor(S8, off);
        }
        float i32 = 0.5f / S32, i8 = 0.5f / S8;
#pragma unroll
        for (int f = 0; f < 4; ++f) {
            int j = f * 16 + ccol;
            float wgt = e[f] * i32 + (((j >= r + 25) && (j <= r + 32)) ? e[f] * i8 : 0.f);
            int byt = ((r * 64 + j) * 2) ^ ((r & 7) << 4);
            *reinterpret_cast<bf16*>(reinterpret_cast<char*>(wlds[wv]) + byt) = f2b(wgt);
        }
    }
    // same-wave LDS write->read: ordered by lgkmcnt, no barrier needed

    // ---- PV: wave wv covers output cols [wv*96, wv*96+96)
    short8 wa[2];
#pragma unroll
    for (int ks = 0; ks < 2; ++ks) {
        int byt = ((lrow * 64 + ks * 32 + koff) * 2) ^ ((lrow & 7) << 4);
        wa[ks] = *reinterpret_cast<const short8*>(reinterpret_cast<const char*>(wlds[wv]) + byt);
    }
    const bf16* vbase = vT + (size_t)b * Dd * KROWS + L0;
    bf16* obase = merged + ((size_t)(b * Ll + L0 + ccol)) * Dd;
#pragma unroll
    for (int fn = 0; fn < 6; ++fn) {
        int nr = wv * 96 + fn * 16;
        floatx4 acc = {};
#pragma unroll
        for (int ks = 0; ks < 2; ++ks) {
            short8 bb = *reinterpret_cast<const short8*>(vbase + (size_t)(nr + lrow) * KROWS + ks * 32 + koff);
            acc = __builtin_amdgcn_mfma_f32_16x16x32_bf16(bb, wa[ks], acc, 0, 0, 0);
        }
        short4s pk;
#pragma unroll
        for (int rr = 0; rr < 4; ++rr) pk[rr] = f2bs(acc[rr]);
        *reinterpret_cast<short4s*>(obase + nr + crow) = pk;
    }
}

extern "C" void kernel_launch(void* const* d_in, const int* in_sizes, int n_in,
                              void* d_out, int out_size, void* d_ws, size_t ws_size,
                              hipStream_t stream) {
    const float* hidden = (const float*)d_in[0];
    const float* sal    = (const float*)d_in[1];
    const float* gw1    = (const float*)d_in[2];
    const float* gb1    = (const float*)d_in[3];
    const float* gw2    = (const float*)d_in[4];
    const float* gb2    = (const float*)d_in[5];
    const float* wq     = (const float*)d_in[6];
    const float* bq     = (const float*)d_in[7];
    const float* wk     = (const float*)d_in[8];
    const float* bk     = (const float*)d_in[9];
    const float* wv     = (const float*)d_in[10];
    const float* bv     = (const float*)d_in[11];
    const float* wo     = (const float*)d_in[12];
    const float* bo     = (const float*)d_in[13];
    float* out = (float*)d_out;

    const size_t nBL  = (size_t)BL * Dd;
    const size_t nPad = (size_t)Bb * KROWS * Dd;
    char* p = (char*)d_ws;
    bf16* h_b = (bf16*)p; p += nBL * 2;
    bf16* q_b = (bf16*)p; p += nBL * 2;
    bf16* kpd = (bf16*)p; p += nPad * 2;
    bf16* vT  = (bf16*)p; p += nPad * 2;
    bf16* m_b = (bf16*)p; p += nBL * 2;
    bf16* w_b = (bf16*)p; p += (size_t)4 * Dd * Dd * 2;

    // MEASUREMENT ROUND 2: prep_gate, attn, gemm_out are idempotent; launch 3x each.
    // (dur - 68.6)/2 ~= t_prep + t_attn + t_out + 3*gap. Revert to 1x next round.
    prep_gate_kernel<<<dim3(PREP_VB + GATE_VB), 256, 0, stream>>>(
        wq, wk, wv, wo, bk, bv, hidden, sal, gw1, gb1, gw2, gb2, w_b, kpd, vT, h_b);
    prep_gate_kernel<<<dim3(PREP_VB + GATE_VB), 256, 0, stream>>>(
        wq, wk, wv, wo, bk, bv, hidden, sal, gw1, gb1, gw2, gb2, w_b, kpd, vT, h_b);
    prep_gate_kernel<<<dim3(PREP_VB + GATE_VB), 256, 0, stream>>>(
        wq, wk, wv, wo, bk, bv, hidden, sal, gw1, gb1, gw2, gb2, w_b, kpd, vT, h_b);
    gemm_qkv<<<dim3(576), 256, 0, stream>>>(h_b, w_b, bq, bk, bv, q_b, kpd, vT);
    attn_kernel<<<dim3(256), 512, 0, stream>>>(q_b, kpd, vT, m_b);
    attn_kernel<<<dim3(256), 512, 0, stream>>>(q_b, kpd, vT, m_b);
    attn_kernel<<<dim3(256), 512, 0, stream>>>(q_b, kpd, vT, m_b);
    gemm_out<<<dim3(384), 256, 0, stream>>>(m_b, w_b + (size_t)3 * Dd * Dd, bo, h_b, out);
    gemm_out<<<dim3(384), 256, 0, stream>>>(m_b, w_b + (size_t)3 * Dd * Dd, bo, h_b, out);
    gemm_out<<<dim3(384), 256, 0, stream>>>(m_b, w_b + (size_t)3 * Dd * Dd, bo, h_b, out);
}

// Round 15
// 67.735 us; speedup vs baseline: 2.1987x; 2.1987x over previous
//
#include <hip/hip_runtime.h>
#include <hip/hip_bf16.h>
#include <stdint.h>

#define Bb 2
#define Ll 2048
#define Dd 768
#define HID 32
#define BL (Bb*Ll)          // 4096
#define KPAD 32
#define KROWS (KPAD+Ll+16)  // 2096

typedef __hip_bfloat16 bf16;
typedef __attribute__((ext_vector_type(8))) short short8;
typedef __attribute__((ext_vector_type(4))) short short4s;
typedef __attribute__((ext_vector_type(4))) float floatx4;

__device__ __forceinline__ float b2f(short u) {
    union { float f; unsigned i; } x; x.i = ((unsigned)(unsigned short)u) << 16; return x.f;
}
__device__ __forceinline__ bf16 f2b(float x) { return __float2bfloat16(x); }
__device__ __forceinline__ short f2bs(float x) {
    bf16 t = __float2bfloat16(x);
    union { bf16 h; short s; } u; u.h = t; return u.s;
}

typedef __attribute__((address_space(1))) const unsigned int guint;
typedef __attribute__((address_space(3))) unsigned int luint;
__device__ __forceinline__ void gload16(const bf16* g, bf16* l) {
    __builtin_amdgcn_global_load_lds((guint*)g, (luint*)l, 16, 0, 0);
}

// ============ prep (weights->bf16, K/V pads) + gate MLP ============
// LDS cut to ~17.5 KB (chunked gw2 transpose) -> 8 blocks/CU for all branches.
#define CONV_VB 2304                 // 4*768*768/4 float4 / 256
#define KP_VB   (Bb*48)              // 96
#define VT_VB   ((Bb*Dd*48)/256)     // 288
#define PREP_VB (CONV_VB+KP_VB+VT_VB)   // 2688
#define GATE_VB (BL/8)               // 512
__global__ __launch_bounds__(256) void prep_gate_kernel(
        const float* __restrict__ wq, const float* __restrict__ wk,
        const float* __restrict__ wv, const float* __restrict__ wo,
        const float* __restrict__ bk, const float* __restrict__ bv,
        const float* __restrict__ hidden, const float* __restrict__ sal,
        const float* __restrict__ gw1, const float* __restrict__ gb1,
        const float* __restrict__ gw2, const float* __restrict__ gb2,
        bf16* __restrict__ wout, bf16* __restrict__ kp, bf16* __restrict__ vT,
        bf16* __restrict__ h_b) {
    __shared__ bf16 g2t[32 * 258];      // one 256-d chunk of gw2^T, stride 258 (bank-clean)
    __shared__ float h1s[8][HID];
    int bx = blockIdx.x, tid = threadIdx.x;
    if (bx < CONV_VB) {
        int idx = bx * 256 + tid;
        const int per = Dd * Dd / 4;
        int w = idx / per, r = idx % per;
        const float* src = (w == 0) ? wq : (w == 1) ? wk : (w == 2) ? wv : wo;
        float4 v = reinterpret_cast<const float4*>(src)[r];
        bf16* o = wout + (size_t)w * Dd * Dd + (size_t)r * 4;
        o[0] = f2b(v.x); o[1] = f2b(v.y); o[2] = f2b(v.z); o[3] = f2b(v.w);
    } else if (bx < CONV_VB + KP_VB) {
        int pb = bx - CONV_VB;
        int b = pb / 48, c = pb % 48;
        int row = (c < 32) ? c : (KPAD + Ll + (c - 32));
        size_t base = ((size_t)b * KROWS + row) * Dd;
        for (int i = tid; i < Dd; i += 256)
            kp[base + i] = (c < 32) ? f2b(bk[i]) : f2b(0.f);
    } else if (bx < PREP_VB) {
        int o = (bx - CONV_VB - KP_VB) * 256 + tid;
        int b = o / (Dd * 48); int rem = o - b * Dd * 48;
        int n = rem / 48, c = rem % 48;
        int col = (c < 32) ? c : (KPAD + Ll + (c - 32));
        vT[((size_t)b * Dd + n) * KROWS + col] = (c < 32) ? f2b(bv[n]) : f2b(0.f);
    } else {
        // ---- gate: 8 rows per block; gw2 transposed in 3 chunks of 256 d ----
        int row0 = (bx - PREP_VB) * 8;
        {
            int rr = tid >> 5, j = tid & 31;
            float s = sal[row0 + rr];
            float x = s * gw1[j] + gb1[j];
            h1s[rr][j] = x / (1.f + __expf(-x));       // silu
        }
        for (int dl = 0; dl < 3; ++dl) {
#pragma unroll
            for (int k2 = 0; k2 < 8; ++k2) {           // 256 d x 32 j fp32 via float4
                int o4 = dl * 2048 + k2 * 256 + tid;
                float4 v = reinterpret_cast<const float4*>(gw2)[o4];
                int dloc = (o4 >> 3) - dl * 256;       // 0..255
                int j0 = (o4 & 7) * 4;
                g2t[(j0 + 0) * 258 + dloc] = f2b(v.x);
                g2t[(j0 + 1) * 258 + dloc] = f2b(v.y);
                g2t[(j0 + 2) * 258 + dloc] = f2b(v.z);
                g2t[(j0 + 3) * 258 + dloc] = f2b(v.w);
            }
            __syncthreads();                            // chunk ready (+h1s on dl=0)
            int d = dl * 256 + tid;
            float base = gb2[d];
            float acc[8];
#pragma unroll
            for (int rr = 0; rr < 8; ++rr) acc[rr] = base;
#pragma unroll
            for (int j = 0; j < HID; ++j) {
                float wj = b2f(*(const short*)&g2t[j * 258 + tid]);  // stride-1, clean
#pragma unroll
                for (int rr = 0; rr < 8; ++rr) acc[rr] += h1s[rr][j] * wj;
            }
#pragma unroll
            for (int rr = 0; rr < 8; ++rr) {
                float g = 1.f / (1.f + __expf(-acc[rr]));
                g = fminf(fmaxf(g, 0.05f), 0.95f);
                size_t off = (size_t)(row0 + rr) * Dd + d;
                h_b[off] = f2b(hidden[off] * g);
            }
            __syncthreads();                            // before overwriting chunk
        }
    }
}

// ---------------- fused QKV GEMM: 128x144 tiles, 512 blocks (2/CU balanced) ----------------
// 4 waves, wave w owns rows [w*32, w*32+32) x all 144 cols; acc[2][9].
__global__ __launch_bounds__(256, 3) void gemm_qkv(
        const bf16* __restrict__ A, const bf16* __restrict__ W3,
        const float* __restrict__ bq, const float* __restrict__ bk, const float* __restrict__ bv,
        bf16* __restrict__ qo, bf16* __restrict__ kp, bf16* __restrict__ vT) {
    __shared__ bf16 As[128 * 64];   // 16 KB
    __shared__ bf16 Bs[144 * 64];   // 18 KB
    int bid = blockIdx.x;
    int xcd = bid & 7, idx = bid >> 3;           // idx 0..63
    int mtile = (xcd >> 1) * 8 + (idx & 7);      // 0..31
    int ntile = (xcd & 1) * 8 + (idx >> 3);      // 0..15
    int m0 = mtile * 128, n0 = ntile * 144;
    const int tid = threadIdx.x;
    const int wave = tid >> 6, lane = tid & 63;
    const int lrow = lane & 15, koff = (lane >> 4) * 8;
    const int wm = wave * 32;
    const char* Asb = (const char*)As;
    const char* Bsb = (const char*)Bs;
    floatx4 acc[2][9] = {};

    for (int k0 = 0; k0 < Dd; k0 += 64) {
#pragma unroll
        for (int c = 0; c < 4; ++c) {            // A: 128x64 = 16 KB
            int p = tid * 16 + c * 4096;
            int r = p >> 7;
            int o = (p & 127) ^ ((r & 7) << 4);
            gload16(A + (size_t)(m0 + r) * Dd + k0 + (o >> 1),
                    As + (wave * 1024 + c * 4096) / 2);
        }
#pragma unroll
        for (int c = 0; c < 4; ++c) {            // B rows 0-127 = 16 KB
            int p = tid * 16 + c * 4096;
            int r = p >> 7;
            int o = (p & 127) ^ ((r & 7) << 4);
            gload16(W3 + (size_t)(n0 + r) * Dd + k0 + (o >> 1),
                    Bs + (wave * 1024 + c * 4096) / 2);
        }
        if (tid < 128) {                         // B rows 128-143 = 2 KB
            int p = 16384 + tid * 16;
            int r = p >> 7;
            int o = (p & 127) ^ ((r & 7) << 4);
            gload16(W3 + (size_t)(n0 + r) * Dd + k0 + (o >> 1),
                    Bs + (16384 + wave * 1024) / 2);
        }
        __syncthreads();
#pragma unroll
        for (int kk = 0; kk < 64; kk += 32) {
            short8 a[2], b[9];
#pragma unroll
            for (int i = 0; i < 2; ++i) {
                int row = wm + i * 16 + lrow;
                int byt = (row << 7) + (((kk + koff) * 2) ^ ((row & 7) << 4));
                a[i] = *reinterpret_cast<const short8*>(Asb + byt);
            }
#pragma unroll
            for (int j = 0; j < 9; ++j) {
                int row = j * 16 + lrow;
                int byt = (row << 7) + (((kk + koff) * 2) ^ ((row & 7) << 4));
                b[j] = *reinterpret_cast<const short8*>(Bsb + byt);
            }
#pragma unroll
            for (int i = 0; i < 2; ++i)
#pragma unroll
                for (int j = 0; j < 9; ++j)
                    acc[i][j] = __builtin_amdgcn_mfma_f32_16x16x32_bf16(a[i], b[j], acc[i][j], 0, 0, 0);
        }
        __syncthreads();
    }

    int crow = (lane >> 4) * 4, ccol = lane & 15;
#pragma unroll
    for (int i = 0; i < 2; ++i)
#pragma unroll
        for (int j = 0; j < 9; ++j) {
            int nf = n0 + j * 16;                // fragment base col (uniform tgt per frag)
            int tgt = nf / 768;
            int nn = nf - tgt * 768 + ccol;
            const float* bias = (tgt == 0) ? bq : (tgt == 1) ? bk : bv;
            float bb = bias[nn];
            int m = m0 + wm + i * 16 + crow;
            int b_ = m >> 11, l = m & 2047;
            if (tgt == 2) {
                short4s pk;
#pragma unroll
                for (int rr = 0; rr < 4; ++rr) pk[rr] = f2bs(acc[i][j][rr] + bb);
                *reinterpret_cast<short4s*>(vT + ((size_t)b_ * Dd + nn) * KROWS + KPAD + l) = pk;
            } else if (tgt == 1) {
#pragma unroll
                for (int rr = 0; rr < 4; ++rr)
                    kp[((size_t)b_ * KROWS + KPAD + l + rr) * Dd + nn] = f2b(acc[i][j][rr] + bb);
            } else {
#pragma unroll
                for (int rr = 0; rr < 4; ++rr)
                    qo[(size_t)(m + rr) * Dd + nn] = f2b(acc[i][j][rr] + bb);
            }
        }
}

// ---------------- output GEMM: 64x96 tiles, 512 blocks (2/CU balanced) ----------------
// 4 waves 2x2: wave owns 32x48; acc[2][3]. out = merged @ wo^T + bo + h.
__global__ __launch_bounds__(256, 4) void gemm_out(
        const bf16* __restrict__ A, const bf16* __restrict__ W,
        const float* __restrict__ bias, const bf16* __restrict__ addend,
        float* __restrict__ out) {
    __shared__ bf16 As[64 * 64];    // 8 KB
    __shared__ bf16 Bs[96 * 64];    // 12 KB
    int bid = blockIdx.x;
    int xcd = bid & 7, idx = bid >> 3;           // idx 0..63
    int mtile = (xcd >> 1) * 16 + (idx & 15);    // 0..63
    int ntile = (xcd & 1) * 4 + (idx >> 4);      // 0..7
    int m0 = mtile * 64, n0 = ntile * 96;
    const int tid = threadIdx.x;
    const int wave = tid >> 6, lane = tid & 63;
    const int lrow = lane & 15, koff = (lane >> 4) * 8;
    const int wm = (wave >> 1) * 32, wn = (wave & 1) * 48;
    const char* Asb = (const char*)As;
    const char* Bsb = (const char*)Bs;
    floatx4 acc[2][3] = {};

    for (int k0 = 0; k0 < Dd; k0 += 64) {
#pragma unroll
        for (int c = 0; c < 2; ++c) {            // A: 64x64 = 8 KB
            int p = tid * 16 + c * 4096;
            int r = p >> 7;
            int o = (p & 127) ^ ((r & 7) << 4);
            gload16(A + (size_t)(m0 + r) * Dd + k0 + (o >> 1),
                    As + (wave * 1024 + c * 4096) / 2);
        }
#pragma unroll
        for (int c = 0; c < 3; ++c) {            // B: 96x64 = 12 KB
            int p = tid * 16 + c * 4096;
            int r = p >> 7;
            int o = (p & 127) ^ ((r & 7) << 4);
            gload16(W + (size_t)(n0 + r) * Dd + k0 + (o >> 1),
                    Bs + (wave * 1024 + c * 4096) / 2);
        }
        __syncthreads();
#pragma unroll
        for (int kk = 0; kk < 64; kk += 32) {
            short8 a[2], b[3];
#pragma unroll
            for (int i = 0; i < 2; ++i) {
                int row = wm + i * 16 + lrow;
                int byt = (row << 7) + (((kk + koff) * 2) ^ ((row & 7) << 4));
                a[i] = *reinterpret_cast<const short8*>(Asb + byt);
            }
#pragma unroll
            for (int j = 0; j < 3; ++j) {
                int row = wn + j * 16 + lrow;
                int byt = (row << 7) + (((kk + koff) * 2) ^ ((row & 7) << 4));
                b[j] = *reinterpret_cast<const short8*>(Bsb + byt);
            }
#pragma unroll
            for (int i = 0; i < 2; ++i)
#pragma unroll
                for (int j = 0; j < 3; ++j)
                    acc[i][j] = __builtin_amdgcn_mfma_f32_16x16x32_bf16(a[i], b[j], acc[i][j], 0, 0, 0);
        }
        __syncthreads();
    }

    int crow = (lane >> 4) * 4, ccol = lane & 15;
#pragma unroll
    for (int i = 0; i < 2; ++i)
#pragma unroll
        for (int j = 0; j < 3; ++j) {
            int n = n0 + wn + j * 16 + ccol;
            float bb = bias[n];
#pragma unroll
            for (int rr = 0; rr < 4; ++rr) {
                int m = m0 + wm + i * 16 + crow + rr;
                size_t o = (size_t)m * Dd + n;
                out[o] = acc[i][j][rr] + bb + b2f(*(const short*)(addend + o));
            }
        }
}

// ---------------- MFMA banded sliding-window attention, 8 waves per group ----------------
#define AW 8
__global__ __launch_bounds__(512) void attn_kernel(
        const bf16* __restrict__ q, const bf16* __restrict__ kp, const bf16* __restrict__ vT,
        bf16* __restrict__ merged) {
    __shared__ float Sp[AW][16][66];       // partial scores; stride 66 -> 2-way banks (free)
    __shared__ bf16 wlds[AW][16 * 64];     // per-wave W~ bounce, XOR-swizzled
    const int tid = threadIdx.x;
    const int wv = tid >> 6, lane = tid & 63;
    const int bid = blockIdx.x;                    // 256
    const int g = (bid & 7) * 32 + (bid >> 3);     // XCD-chunked, bijective
    const int b = g >> 7, L0 = (g & 127) * 16;
    const int lrow = lane & 15, koff = (lane >> 4) * 8;
    const int crow = (lane >> 4) * 4, ccol = lane & 15;
    const float scale = 0.03608439182435161f;      // 1/sqrt(768)

    // ---- QK^T partial: wave wv covers k-dims [wv*96, wv*96+96)
    const bf16* qbase = q  + ((size_t)(b * Ll + L0 + lrow)) * Dd + koff + wv * 96;
    const bf16* kbase = kp + ((size_t)b * KROWS + L0 + lrow) * Dd + koff + wv * 96;
    floatx4 s4[4] = {};
#pragma unroll
    for (int ks = 0; ks < 3; ++ks) {
        short8 a = *reinterpret_cast<const short8*>(qbase + ks * 32);
#pragma unroll
        for (int f = 0; f < 4; ++f) {
            short8 bb = *reinterpret_cast<const short8*>(kbase + (size_t)f * 16 * Dd + ks * 32);
            s4[f] = __builtin_amdgcn_mfma_f32_16x16x32_bf16(a, bb, s4[f], 0, 0, 0);
        }
    }
#pragma unroll
    for (int f = 0; f < 4; ++f)
#pragma unroll
        for (int rr = 0; rr < 4; ++rr)
            Sp[wv][crow + rr][f * 16 + ccol] = s4[f][rr];
    __syncthreads();

    // ---- banded softmax (redundant per wave), rows r = crow+rr; lane col j = f*16+ccol
#pragma unroll
    for (int rr = 0; rr < 4; ++rr) {
        int r = crow + rr;
        float z[4], e[4];
#pragma unroll
        for (int f = 0; f < 4; ++f) {
            int j = f * 16 + ccol;
            float v = 0.f;
#pragma unroll
            for (int w = 0; w < AW; ++w) v += Sp[w][r][j];
            bool valid = (j >= r + 1) && (j <= r + 32);
            z[f] = valid ? v * scale : -3.0e38f;
        }
        float m = fmaxf(fmaxf(z[0], z[1]), fmaxf(z[2], z[3]));
#pragma unroll
        for (int off = 1; off < 16; off <<= 1) m = fmaxf(m, __shfl_xor(m, off));
        float S32 = 0.f, S8 = 0.f;
#pragma unroll
        for (int f = 0; f < 4; ++f) {
            e[f] = __expf(z[f] - m);
            S32 += e[f];
            int j = f * 16 + ccol;
            S8 += ((j >= r + 25) && (j <= r + 32)) ? e[f] : 0.f;
        }
#pragma unroll
        for (int off = 1; off < 16; off <<= 1) {
            S32 += __shfl_xor(S32, off);
            S8  += __shfl_xor(S8, off);
        }
        float i32 = 0.5f / S32, i8 = 0.5f / S8;
#pragma unroll
        for (int f = 0; f < 4; ++f) {
            int j = f * 16 + ccol;
            float wgt = e[f] * i32 + (((j >= r + 25) && (j <= r + 32)) ? e[f] * i8 : 0.f);
            int byt = ((r * 64 + j) * 2) ^ ((r & 7) << 4);
            *reinterpret_cast<bf16*>(reinterpret_cast<char*>(wlds[wv]) + byt) = f2b(wgt);
        }
    }
    // same-wave LDS write->read: ordered by lgkmcnt, no barrier needed

    // ---- PV: wave wv covers output cols [wv*96, wv*96+96)
    short8 wa[2];
#pragma unroll
    for (int ks = 0; ks < 2; ++ks) {
        int byt = ((lrow * 64 + ks * 32 + koff) * 2) ^ ((lrow & 7) << 4);
        wa[ks] = *reinterpret_cast<const short8*>(reinterpret_cast<const char*>(wlds[wv]) + byt);
    }
    const bf16* vbase = vT + (size_t)b * Dd * KROWS + L0;
    bf16* obase = merged + ((size_t)(b * Ll + L0 + ccol)) * Dd;
#pragma unroll
    for (int fn = 0; fn < 6; ++fn) {
        int nr = wv * 96 + fn * 16;
        floatx4 acc = {};
#pragma unroll
        for (int ks = 0; ks < 2; ++ks) {
            short8 bb = *reinterpret_cast<const short8*>(vbase + (size_t)(nr + lrow) * KROWS + ks * 32 + koff);
            acc = __builtin_amdgcn_mfma_f32_16x16x32_bf16(bb, wa[ks], acc, 0, 0, 0);
        }
        short4s pk;
#pragma unroll
        for (int rr = 0; rr < 4; ++rr) pk[rr] = f2bs(acc[rr]);
        *reinterpret_cast<short4s*>(obase + nr + crow) = pk;
    }
}

extern "C" void kernel_launch(void* const* d_in, const int* in_sizes, int n_in,
                              void* d_out, int out_size, void* d_ws, size_t ws_size,
                              hipStream_t stream) {
    const float* hidden = (const float*)d_in[0];
    const float* sal    = (const float*)d_in[1];
    const float* gw1    = (const float*)d_in[2];
    const float* gb1    = (const float*)d_in[3];
    const float* gw2    = (const float*)d_in[4];
    const float* gb2    = (const float*)d_in[5];
    const float* wq     = (const float*)d_in[6];
    const float* bq     = (const float*)d_in[7];
    const float* wk     = (const float*)d_in[8];
    const float* bk     = (const float*)d_in[9];
    const float* wv     = (const float*)d_in[10];
    const float* bv     = (const float*)d_in[11];
    const float* wo     = (const float*)d_in[12];
    const float* bo     = (const float*)d_in[13];
    float* out = (float*)d_out;

    const size_t nBL  = (size_t)BL * Dd;
    const size_t nPad = (size_t)Bb * KROWS * Dd;
    char* p = (char*)d_ws;
    bf16* h_b = (bf16*)p; p += nBL * 2;
    bf16* q_b = (bf16*)p; p += nBL * 2;
    bf16* kpd = (bf16*)p; p += nPad * 2;
    bf16* vT  = (bf16*)p; p += nPad * 2;
    bf16* m_b = (bf16*)p; p += nBL * 2;
    bf16* w_b = (bf16*)p; p += (size_t)4 * Dd * Dd * 2;

    prep_gate_kernel<<<dim3(PREP_VB + GATE_VB), 256, 0, stream>>>(
        wq, wk, wv, wo, bk, bv, hidden, sal, gw1, gb1, gw2, gb2, w_b, kpd, vT, h_b);
    gemm_qkv<<<dim3(512), 256, 0, stream>>>(h_b, w_b, bq, bk, bv, q_b, kpd, vT);
    attn_kernel<<<dim3(256), 512, 0, stream>>>(q_b, kpd, vT, m_b);
    gemm_out<<<dim3(512), 256, 0, stream>>>(m_b, w_b + (size_t)3 * Dd * Dd, bo, h_b, out);
}